// Round 3
// baseline (823.351 us; speedup 1.0000x reference)
//
#include <hip/hip_runtime.h>
#include <hip/hip_bf16.h>
#include <stdint.h>

// Problem constants (fixed by reference)
#define DIMN    2048
#define HIDDEN  2048
#define NHEADS  4
#define HDIM    512
#define BATCH   4
#define SEQ     2048
#define NTOK    (BATCH*SEQ)      // 8192 tokens
#define G4      (4*HIDDEN)       // 8192 gate width
#define EPSV    1e-6f

typedef short short8 __attribute__((ext_vector_type(8)));
typedef float floatx4 __attribute__((ext_vector_type(4)));

union BV8 { uint4 u; __hip_bfloat16 h[8]; unsigned short s[8]; };

__device__ __forceinline__ float fast_sigmoid(float x) {
    return 1.0f / (1.0f + __expf(-x));
}
__device__ __forceinline__ float fast_tanh(float x) {
    return 1.0f - 2.0f / (__expf(2.0f * x) + 1.0f);
}
__device__ __forceinline__ float b2f(unsigned short u) {
    union { unsigned int ui; float f; } v; v.ui = ((unsigned int)u) << 16; return v.f;
}

// ---------------------------------------------------------------------------
// f32 -> bf16 cast, 8 elems/thread
// ---------------------------------------------------------------------------
__global__ __launch_bounds__(256) void cast_f32_bf16(
    const float* __restrict__ in, __hip_bfloat16* __restrict__ out, int n8)
{
    int i = blockIdx.x * 256 + threadIdx.x;
    if (i >= n8) return;
    const float4* p = (const float4*)(in + (size_t)i * 8);
    float4 a = p[0], b = p[1];
    BV8 v;
    v.h[0] = __float2bfloat16(a.x); v.h[1] = __float2bfloat16(a.y);
    v.h[2] = __float2bfloat16(a.z); v.h[3] = __float2bfloat16(a.w);
    v.h[4] = __float2bfloat16(b.x); v.h[5] = __float2bfloat16(b.y);
    v.h[6] = __float2bfloat16(b.z); v.h[7] = __float2bfloat16(b.w);
    *(uint4*)(out + (size_t)i * 8) = v.u;
}

// ---------------------------------------------------------------------------
// GEMM: C[M][N] = A[M][K] @ Bt[N][K]^T   (bf16 in, fp32 acc)
// 128x128 tile, BK=64, 256 threads = 4 waves (2x2), each wave 64x64 (4x4 MFMA)
// EPILOGUE: 0 = store bf16; 1 = bias + gate activations -> bf16; 2 = store f32
// ASRC: 0 = A rows contiguous (stride lda); 1 = head-gather from gates i-slot:
//       element (row, k) at Ag[row*lda + (k>>9)*2048 + (k&511)]
// ---------------------------------------------------------------------------
template <int EPILOGUE, int ASRC>
__global__ __launch_bounds__(256) void gemm_bt(
    const __hip_bfloat16* __restrict__ A,
    const __hip_bfloat16* __restrict__ Bt,
    void* __restrict__ Cout,
    const float* __restrict__ bias,
    int M, int N, int K, int lda)
{
    const int bm = blockIdx.y, bn = blockIdx.x;
    const int tid = threadIdx.x;
    const int wave = tid >> 6, lane = tid & 63;
    const int wm = wave >> 1, wn = wave & 1;
    const int quad = lane >> 4, lr = lane & 15;

    // padded row stride 72 shorts (144B)
    __shared__ __align__(16) short sA[128 * 72];
    __shared__ __align__(16) short sB[128 * 72];

    floatx4 acc[4][4];
#pragma unroll
    for (int i = 0; i < 4; ++i)
#pragma unroll
        for (int j = 0; j < 4; ++j) acc[i][j] = (floatx4)0.0f;

    const short* Ag = (const short*)A + (size_t)(bm * 128) * lda;
    const short* Bg = (const short*)Bt + (size_t)(bn * 128) * K;

    const int srow = tid >> 3;        // 0..31 (plus r*32)
    const int scol = (tid & 7) * 8;   // element offset within 64-wide K-slab

    for (int kb = 0; kb < K; kb += 64) {
        int k = kb + scol;
        size_t acol = (ASRC == 0) ? (size_t)k
                                  : (size_t)((k >> 9) * 2048 + (k & 511));
#pragma unroll
        for (int r = 0; r < 4; ++r) {
            int row = r * 32 + srow;
            uint4 va = *(const uint4*)(Ag + (size_t)row * lda + acol);
            uint4 vb = *(const uint4*)(Bg + (size_t)row * K + k);
            *(uint4*)&sA[row * 72 + scol] = va;
            *(uint4*)&sB[row * 72 + scol] = vb;
        }
        __syncthreads();
#pragma unroll
        for (int kc = 0; kc < 2; ++kc) {
            const int ko = kc * 32 + quad * 8;
            short8 af[4], bfr[4];
#pragma unroll
            for (int mt = 0; mt < 4; ++mt)
                af[mt] = *(const short8*)&sA[(wm * 64 + mt * 16 + lr) * 72 + ko];
#pragma unroll
            for (int nt = 0; nt < 4; ++nt)
                bfr[nt] = *(const short8*)&sB[(wn * 64 + nt * 16 + lr) * 72 + ko];
#pragma unroll
            for (int mt = 0; mt < 4; ++mt)
#pragma unroll
                for (int nt = 0; nt < 4; ++nt)
                    acc[mt][nt] = __builtin_amdgcn_mfma_f32_16x16x32_bf16(
                        af[mt], bfr[nt], acc[mt][nt], 0, 0, 0);
        }
        __syncthreads();
    }

    // epilogue: row = bm*128 + wm*64 + mt*16 + quad*4 + r; col = bn*128 + wn*64 + nt*16 + lr
    const int colbase = bn * 128 + wn * 64;
    const int rowbase = bm * 128 + wm * 64;

    if (EPILOGUE == 0) {
        __hip_bfloat16* O = (__hip_bfloat16*)Cout;
#pragma unroll
        for (int mt = 0; mt < 4; ++mt)
#pragma unroll
            for (int nt = 0; nt < 4; ++nt)
#pragma unroll
                for (int r = 0; r < 4; ++r) {
                    int row = rowbase + mt * 16 + quad * 4 + r;
                    int col = colbase + nt * 16 + lr;
                    O[(size_t)row * N + col] = __float2bfloat16(acc[mt][nt][r]);
                }
    } else if (EPILOGUE == 1) {
        __hip_bfloat16* O = (__hip_bfloat16*)Cout;
#pragma unroll
        for (int nt = 0; nt < 4; ++nt) {
            int col = colbase + nt * 16 + lr;
            int g = (col >> 9) & 3;   // uniform within a 16-col MFMA tile
            float bv = bias[col];
#pragma unroll
            for (int mt = 0; mt < 4; ++mt)
#pragma unroll
                for (int r = 0; r < 4; ++r) {
                    int row = rowbase + mt * 16 + quad * 4 + r;
                    float v = acc[mt][nt][r] + bv;
                    if (g == 0)       v = __expf(v);
                    else if (g == 3)  v = fast_tanh(v);
                    else              v = fast_sigmoid(v);
                    O[(size_t)row * N + col] = __float2bfloat16(v);
                }
        }
    } else {
        float* O = (float*)Cout;
#pragma unroll
        for (int mt = 0; mt < 4; ++mt)
#pragma unroll
            for (int nt = 0; nt < 4; ++nt)
#pragma unroll
                for (int r = 0; r < 4; ++r) {
                    int row = rowbase + mt * 16 + quad * 4 + r;
                    int col = colbase + nt * 16 + lr;
                    O[(size_t)row * N + col] = acc[mt][nt][r];
                }
    }
}

// ---------------------------------------------------------------------------
// Recurrent scan: c_t = f_t*c_{t-1} + i_t*cd_t, per-dim independent.
// 128 blocks x 64 threads = one thread per (b, h*512+d). Software-pipelined:
// double-buffered groups of 8 timesteps so next group's 24 loads overlap the
// current group's FMA chain. Writes c (bf16) to cbuf [tok][HIDDEN] col h*512+d.
// gates col layout: h*2048 + g*512 + d; g: 0=i 1=f 2=o 3=cd (already activated)
// ---------------------------------------------------------------------------
struct G8 { unsigned short i[8], f[8], c[8]; };

__device__ __forceinline__ void load_g8(const unsigned short* __restrict__ g,
                                        int t0, G8& o)
{
#pragma unroll
    for (int j = 0; j < 8; ++j) {
        const unsigned short* gp = g + (size_t)(t0 + j) * G4;
        o.i[j] = gp[0]; o.f[j] = gp[512]; o.c[j] = gp[1536];
    }
}
__device__ __forceinline__ float comp_g8(const G8& gg, float c,
                                         __hip_bfloat16* __restrict__ cb, int t0)
{
#pragma unroll
    for (int j = 0; j < 8; ++j) {
        float iv = b2f(gg.i[j]);
        float fv = b2f(gg.f[j]);
        float cd = b2f(gg.c[j]);
        c = fmaf(fv, c, iv * cd);
        cb[(size_t)(t0 + j) * HIDDEN] = __float2bfloat16(c);
    }
    return c;
}

__global__ __launch_bounds__(64) void scan_kernel(
    const __hip_bfloat16* __restrict__ gates, __hip_bfloat16* __restrict__ cbuf)
{
    int blk = blockIdx.x;            // 0..127
    int bh = blk >> 3, dc = blk & 7;
    int b = bh >> 2, h = bh & 3;
    int d = dc * 64 + threadIdx.x;   // 0..511
    const unsigned short* g = (const unsigned short*)gates
        + (size_t)b * SEQ * G4 + h * 2048 + d;
    __hip_bfloat16* cb = cbuf + (size_t)b * SEQ * HIDDEN + h * 512 + d;

    G8 A, B;
    load_g8(g, 0, A);
    float c = 0.0f;
    for (int t0 = 0; t0 < SEQ; t0 += 16) {
        load_g8(g, t0 + 8, B);
        c = comp_g8(A, c, cb, t0);
        if (t0 + 16 < SEQ) load_g8(g, t0 + 16, A);
        c = comp_g8(B, c, cb, t0 + 8);
    }
}

// ---------------------------------------------------------------------------
// RMS-norm over HD=512 per (b,t,h), then h = o * tanh(c_norm). One wave per
// (b,t,h), 8 dims/lane, shuffle reduction. Writes h (bf16) IN-PLACE into the
// i-gate slot of gates (col h*2048 + d) for GEMM3's head-gather A staging.
// ---------------------------------------------------------------------------
__global__ __launch_bounds__(64) void norm_kernel(
    const __hip_bfloat16* __restrict__ cbuf, __hip_bfloat16* __restrict__ gates,
    const float* __restrict__ rms_w)
{
    int blk = blockIdx.x;                 // B*SEQ*H = 32768
    int h = blk & 3;
    int t = (blk >> 2) & (SEQ - 1);
    int b = blk >> 13;
    int lane = threadIdx.x;
    size_t tok = (size_t)(b * SEQ + t);

    BV8 cv; cv.u = *(const uint4*)(cbuf + tok * HIDDEN + h * 512 + lane * 8);
    float cf[8]; float s = 0.0f;
#pragma unroll
    for (int j = 0; j < 8; ++j) { cf[j] = b2f(cv.s[j]); s += cf[j] * cf[j]; }
#pragma unroll
    for (int off = 32; off > 0; off >>= 1) s += __shfl_xor(s, off, 64);
    float rs = rsqrtf(s * (1.0f / 512.0f) + EPSV);

    BV8 ov; ov.u = *(const uint4*)(gates + tok * G4 + h * 2048 + 1024 + lane * 8);
    float4 w0 = *(const float4*)&rms_w[lane * 8];
    float4 w1 = *(const float4*)&rms_w[lane * 8 + 4];
    float w[8] = { w0.x, w0.y, w0.z, w0.w, w1.x, w1.y, w1.z, w1.w };

    BV8 hv;
#pragma unroll
    for (int j = 0; j < 8; ++j) {
        float o = b2f(ov.s[j]);
        hv.h[j] = __float2bfloat16(o * fast_tanh(cf[j] * rs * w[j]));
    }
    *(uint4*)(gates + tok * G4 + h * 2048 + lane * 8) = hv.u;
}

// ---------------------------------------------------------------------------
// Workspace plan (192 MiB total, lifetime-aliased):
//  [0,  32MiB)  wgb  (bf16 W_gate)          ... after GEMM2: first 8MiB = wob
//  [32, 64MiB)  xpb  (bf16 GEMM1 out)       ... after GEMM2: cbuf (bf16 c)
//  [64,192MiB)  gates (bf16 activated)      ... before GEMM2: wib + xb
// ---------------------------------------------------------------------------
extern "C" void kernel_launch(void* const* d_in, const int* in_sizes, int n_in,
                              void* d_out, int out_size, void* d_ws, size_t ws_size,
                              hipStream_t stream)
{
    const float* x      = (const float*)d_in[0];   // (4,2048,2048)
    const float* W_in   = (const float*)d_in[1];   // (2048,2048)
    const float* W_gate = (const float*)d_in[2];   // (8192,2048)
    const float* b_gate = (const float*)d_in[3];   // (8192,)
    const float* rms_w  = (const float*)d_in[4];   // (512,)
    const float* W_out  = (const float*)d_in[5];   // (2048,2048)
    float* out = (float*)d_out;                    // (4,2048,2048)

    char* base = (char*)d_ws;
    __hip_bfloat16* wgb   = (__hip_bfloat16*)base;                             // 32 MiB
    __hip_bfloat16* xpb   = (__hip_bfloat16*)(base + (((size_t)32) << 20));    // 32 MiB
    __hip_bfloat16* gates = (__hip_bfloat16*)(base + (((size_t)64) << 20));    // 128 MiB
    // aliases (lifetime-disjoint, stream-ordered):
    __hip_bfloat16* wib  = gates;                                              // 8 MiB
    __hip_bfloat16* xb   = (__hip_bfloat16*)(base + (((size_t)72) << 20));     // 32 MiB
    __hip_bfloat16* wob  = wgb;                                                // 8 MiB
    __hip_bfloat16* cbuf = xpb;                                                // 32 MiB

    // 1) casts to bf16 (wib/xb live in gates region; gates not written yet)
    cast_f32_bf16<<<(HIDDEN * DIMN) / 8 / 256, 256, 0, stream>>>(W_in, wib, (HIDDEN * DIMN) / 8);
    cast_f32_bf16<<<(NTOK * DIMN) / 8 / 256, 256, 0, stream>>>(x, xb, (NTOK * DIMN) / 8);
    cast_f32_bf16<<<(G4 * HIDDEN) / 8 / 256, 256, 0, stream>>>(W_gate, wgb, (G4 * HIDDEN) / 8);

    // 2) xp = x @ W_in^T  -> bf16
    {
        dim3 grid(HIDDEN / 128, NTOK / 128);
        gemm_bt<0, 0><<<grid, 256, 0, stream>>>(xb, wib, xpb, nullptr,
                                                NTOK, HIDDEN, DIMN, DIMN);
    }
    // 3) gates = act(xp @ W_gate^T + b) -> bf16 (overwrites wib/xb: dead now)
    {
        dim3 grid(G4 / 128, NTOK / 128);
        gemm_bt<1, 0><<<grid, 256, 0, stream>>>(xpb, wgb, gates, b_gate,
                                                NTOK, G4, HIDDEN, HIDDEN);
    }
    // 4) cast W_out -> wob (overwrites wgb: dead now)
    cast_f32_bf16<<<(DIMN * HIDDEN) / 8 / 256, 256, 0, stream>>>(W_out, wob, (DIMN * HIDDEN) / 8);

    // 5) recurrent scan -> cbuf (bf16; overwrites xpb: dead now)
    scan_kernel<<<BATCH * NHEADS * 8, 64, 0, stream>>>(gates, cbuf);

    // 6) RMS-norm + output gate; h written into gates i-slot
    norm_kernel<<<BATCH * SEQ * NHEADS, 64, 0, stream>>>(cbuf, gates, rms_w);

    // 7) out = h @ W_out^T -> f32 (A head-gathered from gates i-slot)
    {
        dim3 grid(DIMN / 128, NTOK / 128);
        gemm_bt<2, 1><<<grid, 256, 0, stream>>>(gates, wob, out, nullptr,
                                                NTOK, DIMN, HIDDEN, G4);
    }
}

// Round 4
// 757.804 us; speedup vs baseline: 1.0865x; 1.0865x over previous
//
#include <hip/hip_runtime.h>
#include <hip/hip_bf16.h>
#include <stdint.h>

// Problem constants (fixed by reference)
#define DIMN    2048
#define HIDDEN  2048
#define NHEADS  4
#define HDIM    512
#define BATCH   4
#define SEQ     2048
#define NTOK    (BATCH*SEQ)      // 8192 tokens
#define G4      (4*HIDDEN)       // 8192 gate width
#define EPSV    1e-6f

typedef short short8 __attribute__((ext_vector_type(8)));
typedef float floatx4 __attribute__((ext_vector_type(4)));

union BV8 { uint4 u; __hip_bfloat16 h[8]; unsigned short s[8]; };

__device__ __forceinline__ float fast_sigmoid(float x) {
    return 1.0f / (1.0f + __expf(-x));
}
__device__ __forceinline__ float fast_tanh(float x) {
    return 1.0f - 2.0f / (__expf(2.0f * x) + 1.0f);
}
__device__ __forceinline__ float b2f(unsigned short u) {
    union { unsigned int ui; float f; } v; v.ui = ((unsigned int)u) << 16; return v.f;
}

// async global->LDS, 16B per lane; LDS dest = wave-uniform base + lane*16
__device__ __forceinline__ void gld_lds16(const void* gp, void* lp) {
    __builtin_amdgcn_global_load_lds(
        (const __attribute__((address_space(1))) void*)gp,
        (__attribute__((address_space(3))) void*)lp, 16, 0, 0);
}

// ---------------------------------------------------------------------------
// f32 -> bf16 cast, 8 elems/thread
// ---------------------------------------------------------------------------
__global__ __launch_bounds__(256) void cast_f32_bf16(
    const float* __restrict__ in, __hip_bfloat16* __restrict__ out, int n8)
{
    int i = blockIdx.x * 256 + threadIdx.x;
    if (i >= n8) return;
    const float4* p = (const float4*)(in + (size_t)i * 8);
    float4 a = p[0], b = p[1];
    BV8 v;
    v.h[0] = __float2bfloat16(a.x); v.h[1] = __float2bfloat16(a.y);
    v.h[2] = __float2bfloat16(a.z); v.h[3] = __float2bfloat16(a.w);
    v.h[4] = __float2bfloat16(b.x); v.h[5] = __float2bfloat16(b.y);
    v.h[6] = __float2bfloat16(b.z); v.h[7] = __float2bfloat16(b.w);
    *(uint4*)(out + (size_t)i * 8) = v.u;
}

// ---------------------------------------------------------------------------
// GEMM: C[M][N] = A[M][K] @ Bt[N][K]^T   (bf16 in, fp32 acc)
// 128x128 tile, BK=64, 256 threads = 4 waves (2x2), each wave 64x64 (4x4 MFMA)
// m97-style staging: global_load_lds dwordx4, unpadded [128][64] LDS tiles,
// XOR swizzle on the SOURCE chunk (LDS[row][c] = G[row][c ^ (row&7)]) so the
// MFMA fragment ds_read_b128s are 2-way-aliased only (free).
// EPILOGUE: 0 = store bf16; 1 = bias + gate activations -> bf16; 2 = store f32
// ASRC: 0 = A rows contiguous (stride lda); 1 = head-gather from gates i-slot:
//       element (row, k) at Ag[row*lda + (k>>9)*2048 + (k&511)]
// ---------------------------------------------------------------------------
template <int EPILOGUE, int ASRC>
__global__ __launch_bounds__(256) void gemm_bt(
    const __hip_bfloat16* __restrict__ A,
    const __hip_bfloat16* __restrict__ Bt,
    void* __restrict__ Cout,
    const float* __restrict__ bias,
    int M, int N, int K, int lda)
{
    const int bm = blockIdx.y, bn = blockIdx.x;
    const int tid = threadIdx.x;
    const int wave = tid >> 6, lane = tid & 63;
    const int wm = wave >> 1, wn = wave & 1;
    const int quad = lane >> 4, lr = lane & 15;

    __shared__ __align__(16) short sA[128 * 64];   // 16 KiB, unpadded
    __shared__ __align__(16) short sB[128 * 64];   // 16 KiB, unpadded

    floatx4 acc[4][4];
#pragma unroll
    for (int i = 0; i < 4; ++i)
#pragma unroll
        for (int j = 0; j < 4; ++j) acc[i][j] = (floatx4)0.0f;

    const short* Ag = (const short*)A + (size_t)(bm * 128) * lda;
    const short* Bg = (const short*)Bt + (size_t)(bn * 128) * K;

    // staging decomposition: lane -> (row-in-8, chunk); source chunk is XOR'd
    const int r8  = lane >> 3;            // 0..7
    const int gcs = ((lane & 7) ^ r8) * 8; // swizzled source chunk offset (shorts)
    const int rl7 = lr & 7;               // read-side swizzle key

    for (int kb = 0; kb < K; kb += 64) {
        size_t acol;
        if (ASRC == 0) acol = (size_t)(kb + gcs);
        else           acol = (size_t)(((kb >> 9) * 2048) + (kb & 511) + gcs);
#pragma unroll
        for (int it = 0; it < 4; ++it) {
            const int rowb = wave * 32 + it * 8;      // wave-uniform LDS row base
            const int grow = rowb + r8;
            gld_lds16(Ag + (size_t)grow * lda + acol,       &sA[rowb * 64]);
            gld_lds16(Bg + (size_t)grow * K + kb + gcs,     &sB[rowb * 64]);
        }
        __syncthreads();
#pragma unroll
        for (int kc = 0; kc < 2; ++kc) {
            const int q = kc * 4 + quad;
            const int co = ((q ^ rl7) << 3);          // swizzled chunk offset
            short8 af[4], bfr[4];
#pragma unroll
            for (int mt = 0; mt < 4; ++mt)
                af[mt] = *(const short8*)&sA[(wm * 64 + mt * 16 + lr) * 64 + co];
#pragma unroll
            for (int nt = 0; nt < 4; ++nt)
                bfr[nt] = *(const short8*)&sB[(wn * 64 + nt * 16 + lr) * 64 + co];
#pragma unroll
            for (int mt = 0; mt < 4; ++mt)
#pragma unroll
                for (int nt = 0; nt < 4; ++nt)
                    acc[mt][nt] = __builtin_amdgcn_mfma_f32_16x16x32_bf16(
                        af[mt], bfr[nt], acc[mt][nt], 0, 0, 0);
        }
        __syncthreads();
    }

    // epilogue: row = bm*128 + wm*64 + mt*16 + quad*4 + r; col = bn*128 + wn*64 + nt*16 + lr
    const int colbase = bn * 128 + wn * 64;
    const int rowbase = bm * 128 + wm * 64;

    if (EPILOGUE == 0) {
        __hip_bfloat16* O = (__hip_bfloat16*)Cout;
#pragma unroll
        for (int mt = 0; mt < 4; ++mt)
#pragma unroll
            for (int nt = 0; nt < 4; ++nt)
#pragma unroll
                for (int r = 0; r < 4; ++r) {
                    int row = rowbase + mt * 16 + quad * 4 + r;
                    int col = colbase + nt * 16 + lr;
                    O[(size_t)row * N + col] = __float2bfloat16(acc[mt][nt][r]);
                }
    } else if (EPILOGUE == 1) {
        __hip_bfloat16* O = (__hip_bfloat16*)Cout;
#pragma unroll
        for (int nt = 0; nt < 4; ++nt) {
            int col = colbase + nt * 16 + lr;
            int g = (col >> 9) & 3;   // uniform within a 16-col MFMA tile
            float bv = bias[col];
#pragma unroll
            for (int mt = 0; mt < 4; ++mt)
#pragma unroll
                for (int r = 0; r < 4; ++r) {
                    int row = rowbase + mt * 16 + quad * 4 + r;
                    float v = acc[mt][nt][r] + bv;
                    if (g == 0)       v = __expf(v);
                    else if (g == 3)  v = fast_tanh(v);
                    else              v = fast_sigmoid(v);
                    O[(size_t)row * N + col] = __float2bfloat16(v);
                }
        }
    } else {
        float* O = (float*)Cout;
#pragma unroll
        for (int mt = 0; mt < 4; ++mt)
#pragma unroll
            for (int nt = 0; nt < 4; ++nt)
#pragma unroll
                for (int r = 0; r < 4; ++r) {
                    int row = rowbase + mt * 16 + quad * 4 + r;
                    int col = colbase + nt * 16 + lr;
                    O[(size_t)row * N + col] = acc[mt][nt][r];
                }
    }
}

// ---------------------------------------------------------------------------
// Recurrent scan: c_t = f_t*c_{t-1} + i_t*cd_t, per-dim independent.
// 128 blocks x 64 threads = one thread per (b, h*512+d). 16-step double-
// buffered pipeline: 48 loads in flight (under the vmcnt=63 cap) to raise
// effective BW (~2 TB/s across 128 waves). Writes c (bf16) to cbuf
// [tok][HIDDEN] col h*512+d. gates col: h*2048 + g*512 + d (g:0=i 1=f 2=o 3=cd)
// ---------------------------------------------------------------------------
struct G16 { unsigned short i[16], f[16], c[16]; };

__device__ __forceinline__ void load_g16(const unsigned short* __restrict__ g,
                                         int t0, G16& o)
{
#pragma unroll
    for (int j = 0; j < 16; ++j) {
        const unsigned short* gp = g + (size_t)(t0 + j) * G4;
        o.i[j] = gp[0]; o.f[j] = gp[512]; o.c[j] = gp[1536];
    }
}
__device__ __forceinline__ float comp_g16(const G16& gg, float c,
                                          __hip_bfloat16* __restrict__ cb, int t0)
{
#pragma unroll
    for (int j = 0; j < 16; ++j) {
        float iv = b2f(gg.i[j]);
        float fv = b2f(gg.f[j]);
        float cd = b2f(gg.c[j]);
        c = fmaf(fv, c, iv * cd);
        cb[(size_t)(t0 + j) * HIDDEN] = __float2bfloat16(c);
    }
    return c;
}

__global__ __launch_bounds__(64) void scan_kernel(
    const __hip_bfloat16* __restrict__ gates, __hip_bfloat16* __restrict__ cbuf)
{
    int blk = blockIdx.x;            // 0..127
    int bh = blk >> 3, dc = blk & 7;
    int b = bh >> 2, h = bh & 3;
    int d = dc * 64 + threadIdx.x;   // 0..511
    const unsigned short* g = (const unsigned short*)gates
        + (size_t)b * SEQ * G4 + h * 2048 + d;
    __hip_bfloat16* cb = cbuf + (size_t)b * SEQ * HIDDEN + h * 512 + d;

    G16 A, B;
    load_g16(g, 0, A);
    float c = 0.0f;
    for (int t0 = 0; t0 < SEQ; t0 += 32) {
        load_g16(g, t0 + 16, B);
        c = comp_g16(A, c, cb, t0);
        if (t0 + 32 < SEQ) load_g16(g, t0 + 32, A);
        c = comp_g16(B, c, cb, t0 + 16);
    }
}

// ---------------------------------------------------------------------------
// RMS-norm over HD=512 per (b,t,h), then h = o * tanh(c_norm). One wave per
// (b,t,h), 8 dims/lane, shuffle reduction. Writes h (bf16) IN-PLACE into the
// i-gate slot of gates (col h*2048 + d) for GEMM3's head-gather A staging.
// ---------------------------------------------------------------------------
__global__ __launch_bounds__(64) void norm_kernel(
    const __hip_bfloat16* __restrict__ cbuf, __hip_bfloat16* __restrict__ gates,
    const float* __restrict__ rms_w)
{
    int blk = blockIdx.x;                 // B*SEQ*H = 32768
    int h = blk & 3;
    int t = (blk >> 2) & (SEQ - 1);
    int b = blk >> 13;
    int lane = threadIdx.x;
    size_t tok = (size_t)(b * SEQ + t);

    BV8 cv; cv.u = *(const uint4*)(cbuf + tok * HIDDEN + h * 512 + lane * 8);
    float cf[8]; float s = 0.0f;
#pragma unroll
    for (int j = 0; j < 8; ++j) { cf[j] = b2f(cv.s[j]); s += cf[j] * cf[j]; }
#pragma unroll
    for (int off = 32; off > 0; off >>= 1) s += __shfl_xor(s, off, 64);
    float rs = rsqrtf(s * (1.0f / 512.0f) + EPSV);

    BV8 ov; ov.u = *(const uint4*)(gates + tok * G4 + h * 2048 + 1024 + lane * 8);
    float4 w0 = *(const float4*)&rms_w[lane * 8];
    float4 w1 = *(const float4*)&rms_w[lane * 8 + 4];
    float w[8] = { w0.x, w0.y, w0.z, w0.w, w1.x, w1.y, w1.z, w1.w };

    BV8 hv;
#pragma unroll
    for (int j = 0; j < 8; ++j) {
        float o = b2f(ov.s[j]);
        hv.h[j] = __float2bfloat16(o * fast_tanh(cf[j] * rs * w[j]));
    }
    *(uint4*)(gates + tok * G4 + h * 2048 + lane * 8) = hv.u;
}

// ---------------------------------------------------------------------------
// Workspace plan (192 MiB total, lifetime-aliased):
//  [0,  32MiB)  wgb  (bf16 W_gate)          ... after GEMM2: first 8MiB = wob
//  [32, 64MiB)  xpb  (bf16 GEMM1 out)       ... after GEMM2: cbuf (bf16 c)
//  [64,192MiB)  gates (bf16 activated)      ... before GEMM2: wib + xb
// ---------------------------------------------------------------------------
extern "C" void kernel_launch(void* const* d_in, const int* in_sizes, int n_in,
                              void* d_out, int out_size, void* d_ws, size_t ws_size,
                              hipStream_t stream)
{
    const float* x      = (const float*)d_in[0];   // (4,2048,2048)
    const float* W_in   = (const float*)d_in[1];   // (2048,2048)
    const float* W_gate = (const float*)d_in[2];   // (8192,2048)
    const float* b_gate = (const float*)d_in[3];   // (8192,)
    const float* rms_w  = (const float*)d_in[4];   // (512,)
    const float* W_out  = (const float*)d_in[5];   // (2048,2048)
    float* out = (float*)d_out;                    // (4,2048,2048)

    char* base = (char*)d_ws;
    __hip_bfloat16* wgb   = (__hip_bfloat16*)base;                             // 32 MiB
    __hip_bfloat16* xpb   = (__hip_bfloat16*)(base + (((size_t)32) << 20));    // 32 MiB
    __hip_bfloat16* gates = (__hip_bfloat16*)(base + (((size_t)64) << 20));    // 128 MiB
    // aliases (lifetime-disjoint, stream-ordered):
    __hip_bfloat16* wib  = gates;                                              // 8 MiB
    __hip_bfloat16* xb   = (__hip_bfloat16*)(base + (((size_t)72) << 20));     // 32 MiB
    __hip_bfloat16* wob  = wgb;                                                // 8 MiB
    __hip_bfloat16* cbuf = xpb;                                                // 32 MiB

    // 1) casts to bf16 (wib/xb live in gates region; gates not written yet)
    cast_f32_bf16<<<(HIDDEN * DIMN) / 8 / 256, 256, 0, stream>>>(W_in, wib, (HIDDEN * DIMN) / 8);
    cast_f32_bf16<<<(NTOK * DIMN) / 8 / 256, 256, 0, stream>>>(x, xb, (NTOK * DIMN) / 8);
    cast_f32_bf16<<<(G4 * HIDDEN) / 8 / 256, 256, 0, stream>>>(W_gate, wgb, (G4 * HIDDEN) / 8);

    // 2) xp = x @ W_in^T  -> bf16
    {
        dim3 grid(HIDDEN / 128, NTOK / 128);
        gemm_bt<0, 0><<<grid, 256, 0, stream>>>(xb, wib, xpb, nullptr,
                                                NTOK, HIDDEN, DIMN, DIMN);
    }
    // 3) gates = act(xp @ W_gate^T + b) -> bf16 (overwrites wib/xb: dead now)
    {
        dim3 grid(G4 / 128, NTOK / 128);
        gemm_bt<1, 0><<<grid, 256, 0, stream>>>(xpb, wgb, gates, b_gate,
                                                NTOK, G4, HIDDEN, HIDDEN);
    }
    // 4) cast W_out -> wob (overwrites wgb: dead now)
    cast_f32_bf16<<<(DIMN * HIDDEN) / 8 / 256, 256, 0, stream>>>(W_out, wob, (DIMN * HIDDEN) / 8);

    // 5) recurrent scan -> cbuf (bf16; overwrites xpb: dead now)
    scan_kernel<<<BATCH * NHEADS * 8, 64, 0, stream>>>(gates, cbuf);

    // 6) RMS-norm + output gate; h written into gates i-slot
    norm_kernel<<<BATCH * SEQ * NHEADS, 64, 0, stream>>>(cbuf, gates, rms_w);

    // 7) out = h @ W_out^T -> f32 (A head-gathered from gates i-slot)
    {
        dim3 grid(DIMN / 128, NTOK / 128);
        gemm_bt<2, 1><<<grid, 256, 0, stream>>>(gates, wob, out, nullptr,
                                                NTOK, DIMN, HIDDEN, G4);
    }
}

// Round 5
// 734.247 us; speedup vs baseline: 1.1214x; 1.0321x over previous
//
#include <hip/hip_runtime.h>
#include <hip/hip_bf16.h>
#include <stdint.h>

// Problem constants (fixed by reference)
#define DIMN    2048
#define HIDDEN  2048
#define NHEADS  4
#define HDIM    512
#define BATCH   4
#define SEQ     2048
#define NTOK    (BATCH*SEQ)      // 8192 tokens
#define G4      (4*HIDDEN)       // 8192 gate width
#define EPSV    1e-6f
#define CHUNK   128
#define NCHUNK  (SEQ/CHUNK)      // 16

typedef short short8 __attribute__((ext_vector_type(8)));
typedef float floatx4 __attribute__((ext_vector_type(4)));

union BV8 { uint4 u; __hip_bfloat16 h[8]; unsigned short s[8]; };

__device__ __forceinline__ float fast_sigmoid(float x) {
    return 1.0f / (1.0f + __expf(-x));
}
__device__ __forceinline__ float fast_tanh(float x) {
    return 1.0f - 2.0f / (__expf(2.0f * x) + 1.0f);
}
__device__ __forceinline__ float b2f(unsigned short u) {
    union { unsigned int ui; float f; } v; v.ui = ((unsigned int)u) << 16; return v.f;
}

// async global->LDS, 16B per lane; LDS dest = wave-uniform base + lane*16
__device__ __forceinline__ void gld_lds16(const void* gp, void* lp) {
    __builtin_amdgcn_global_load_lds(
        (const __attribute__((address_space(1))) void*)gp,
        (__attribute__((address_space(3))) void*)lp, 16, 0, 0);
}

// ---------------------------------------------------------------------------
// f32 -> bf16 cast, 8 elems/thread
// ---------------------------------------------------------------------------
__global__ __launch_bounds__(256) void cast_f32_bf16(
    const float* __restrict__ in, __hip_bfloat16* __restrict__ out, int n8)
{
    int i = blockIdx.x * 256 + threadIdx.x;
    if (i >= n8) return;
    const float4* p = (const float4*)(in + (size_t)i * 8);
    float4 a = p[0], b = p[1];
    BV8 v;
    v.h[0] = __float2bfloat16(a.x); v.h[1] = __float2bfloat16(a.y);
    v.h[2] = __float2bfloat16(a.z); v.h[3] = __float2bfloat16(a.w);
    v.h[4] = __float2bfloat16(b.x); v.h[5] = __float2bfloat16(b.y);
    v.h[6] = __float2bfloat16(b.z); v.h[7] = __float2bfloat16(b.w);
    *(uint4*)(out + (size_t)i * 8) = v.u;
}

// ---------------------------------------------------------------------------
// GEMM: C[M][N] = A[M][K] @ Bt[N][K]^T   (bf16 in, fp32 acc)
// 128x128 tile, BK=64, 256 threads = 4 waves (2x2), each wave 64x64 (4x4 MFMA)
// m97-style staging: global_load_lds dwordx4, unpadded [128][64] LDS tiles,
// XOR swizzle on the SOURCE chunk (LDS[row][c] = G[row][c ^ (row&7)]) so the
// MFMA fragment ds_read_b128s are 2-way-aliased only (free). Verified R4:
// SQ_LDS_BANK_CONFLICT == 0, 823 TF (m97 plateau).
// EPILOGUE: 0 = store bf16; 1 = bias + gate activations -> bf16; 2 = store f32
// ASRC: 0 = A rows contiguous (stride lda); 1 = head-gather from gates i-slot:
//       element (row, k) at Ag[row*lda + (k>>9)*2048 + (k&511)]
// ---------------------------------------------------------------------------
template <int EPILOGUE, int ASRC>
__global__ __launch_bounds__(256) void gemm_bt(
    const __hip_bfloat16* __restrict__ A,
    const __hip_bfloat16* __restrict__ Bt,
    void* __restrict__ Cout,
    const float* __restrict__ bias,
    int M, int N, int K, int lda)
{
    const int bm = blockIdx.y, bn = blockIdx.x;
    const int tid = threadIdx.x;
    const int wave = tid >> 6, lane = tid & 63;
    const int wm = wave >> 1, wn = wave & 1;
    const int quad = lane >> 4, lr = lane & 15;

    __shared__ __align__(16) short sA[128 * 64];   // 16 KiB, unpadded
    __shared__ __align__(16) short sB[128 * 64];   // 16 KiB, unpadded

    floatx4 acc[4][4];
#pragma unroll
    for (int i = 0; i < 4; ++i)
#pragma unroll
        for (int j = 0; j < 4; ++j) acc[i][j] = (floatx4)0.0f;

    const short* Ag = (const short*)A + (size_t)(bm * 128) * lda;
    const short* Bg = (const short*)Bt + (size_t)(bn * 128) * K;

    // staging decomposition: lane -> (row-in-8, chunk); source chunk is XOR'd
    const int r8  = lane >> 3;             // 0..7
    const int gcs = ((lane & 7) ^ r8) * 8; // swizzled source chunk offset (shorts)
    const int rl7 = lr & 7;                // read-side swizzle key

    for (int kb = 0; kb < K; kb += 64) {
        size_t acol;
        if (ASRC == 0) acol = (size_t)(kb + gcs);
        else           acol = (size_t)(((kb >> 9) * 2048) + (kb & 511) + gcs);
#pragma unroll
        for (int it = 0; it < 4; ++it) {
            const int rowb = wave * 32 + it * 8;      // wave-uniform LDS row base
            const int grow = rowb + r8;
            gld_lds16(Ag + (size_t)grow * lda + acol,       &sA[rowb * 64]);
            gld_lds16(Bg + (size_t)grow * K + kb + gcs,     &sB[rowb * 64]);
        }
        __syncthreads();
#pragma unroll
        for (int kc = 0; kc < 2; ++kc) {
            const int q = kc * 4 + quad;
            const int co = ((q ^ rl7) << 3);          // swizzled chunk offset
            short8 af[4], bfr[4];
#pragma unroll
            for (int mt = 0; mt < 4; ++mt)
                af[mt] = *(const short8*)&sA[(wm * 64 + mt * 16 + lr) * 64 + co];
#pragma unroll
            for (int nt = 0; nt < 4; ++nt)
                bfr[nt] = *(const short8*)&sB[(wn * 64 + nt * 16 + lr) * 64 + co];
#pragma unroll
            for (int mt = 0; mt < 4; ++mt)
#pragma unroll
                for (int nt = 0; nt < 4; ++nt)
                    acc[mt][nt] = __builtin_amdgcn_mfma_f32_16x16x32_bf16(
                        af[mt], bfr[nt], acc[mt][nt], 0, 0, 0);
        }
        __syncthreads();
    }

    // epilogue: row = bm*128 + wm*64 + mt*16 + quad*4 + r; col = bn*128 + wn*64 + nt*16 + lr
    const int colbase = bn * 128 + wn * 64;
    const int rowbase = bm * 128 + wm * 64;

    if (EPILOGUE == 0) {
        __hip_bfloat16* O = (__hip_bfloat16*)Cout;
#pragma unroll
        for (int mt = 0; mt < 4; ++mt)
#pragma unroll
            for (int nt = 0; nt < 4; ++nt)
#pragma unroll
                for (int r = 0; r < 4; ++r) {
                    int row = rowbase + mt * 16 + quad * 4 + r;
                    int col = colbase + nt * 16 + lr;
                    O[(size_t)row * N + col] = __float2bfloat16(acc[mt][nt][r]);
                }
    } else if (EPILOGUE == 1) {
        __hip_bfloat16* O = (__hip_bfloat16*)Cout;
#pragma unroll
        for (int nt = 0; nt < 4; ++nt) {
            int col = colbase + nt * 16 + lr;
            int g = (col >> 9) & 3;   // uniform within a 16-col MFMA tile
            float bv = bias[col];
#pragma unroll
            for (int mt = 0; mt < 4; ++mt)
#pragma unroll
                for (int r = 0; r < 4; ++r) {
                    int row = rowbase + mt * 16 + quad * 4 + r;
                    float v = acc[mt][nt][r] + bv;
                    if (g == 0)       v = __expf(v);
                    else if (g == 3)  v = fast_tanh(v);
                    else              v = fast_sigmoid(v);
                    O[(size_t)row * N + col] = __float2bfloat16(v);
                }
        }
    } else {
        float* O = (float*)Cout;
#pragma unroll
        for (int mt = 0; mt < 4; ++mt)
#pragma unroll
            for (int nt = 0; nt < 4; ++nt)
#pragma unroll
                for (int r = 0; r < 4; ++r) {
                    int row = rowbase + mt * 16 + quad * 4 + r;
                    int col = colbase + nt * 16 + lr;
                    O[(size_t)row * N + col] = acc[mt][nt][r];
                }
    }
}

// ---------------------------------------------------------------------------
// Chunk-decomposed linear scan. c_t = f_t*c_{t-1} + i_t*cd_t is linear in c,
// so split SEQ into 16 chunks of 128:
//   pass1: per (dim, chunk) scan from c=0 in f32, keep P = prod(f) in f32;
//          store only chunk summaries cLast/PLast (f32, 1 MB).
//   pass2: per (dim, chunk) compose c_init from preceding summaries
//          in-register (<=15 f32 fmas, exact), re-scan the chunk re-reading
//          gates, store c (bf16) to cbuf.
// Parallelism: 131072 threads = 2048 waves (vs 128 for the monolithic scan).
// Thread map: blk = ((b*4+h)*16 + j)*2 + dh; d = dh*256 + tid (coalesced).
// gates col: h*2048 + g*512 + d (g: 0=i 1=f 2=o 3=cd, already activated).
// ---------------------------------------------------------------------------
struct G16 { unsigned short i[16], f[16], c[16]; };

__device__ __forceinline__ void load_g16(const unsigned short* __restrict__ g,
                                         int t0, G16& o)
{
#pragma unroll
    for (int j = 0; j < 16; ++j) {
        const unsigned short* gp = g + (size_t)(t0 + j) * G4;
        o.i[j] = gp[0]; o.f[j] = gp[512]; o.c[j] = gp[1536];
    }
}
__device__ __forceinline__ void comp_sum16(const G16& gg, float& c, float& P)
{
#pragma unroll
    for (int j = 0; j < 16; ++j) {
        float iv = b2f(gg.i[j]);
        float fv = b2f(gg.f[j]);
        float cd = b2f(gg.c[j]);
        c = fmaf(fv, c, iv * cd);
        P *= fv;
    }
}
__device__ __forceinline__ float comp_store16(const G16& gg, float c,
                                              __hip_bfloat16* __restrict__ cb, int t0)
{
#pragma unroll
    for (int j = 0; j < 16; ++j) {
        float iv = b2f(gg.i[j]);
        float fv = b2f(gg.f[j]);
        float cd = b2f(gg.c[j]);
        c = fmaf(fv, c, iv * cd);
        cb[(size_t)(t0 + j) * HIDDEN] = __float2bfloat16(c);
    }
    return c;
}

__global__ __launch_bounds__(256) void scan_pass1(
    const __hip_bfloat16* __restrict__ gates,
    float* __restrict__ cLast, float* __restrict__ PLast)
{
    int blk = blockIdx.x;              // 0..511
    int dh = blk & 1;
    int j  = (blk >> 1) & 15;
    int bh = blk >> 5;                 // 0..15
    int b = bh >> 2, h = bh & 3;
    int d = dh * 256 + threadIdx.x;    // 0..511
    int bhd = bh * 512 + d;

    const unsigned short* g = (const unsigned short*)gates
        + (size_t)(b * SEQ + j * CHUNK) * G4 + h * 2048 + d;

    float c = 0.0f, P = 1.0f;
    G16 A, B;
    load_g16(g, 0, A);
    for (int t0 = 0; t0 < CHUNK; t0 += 32) {
        load_g16(g, t0 + 16, B);
        comp_sum16(A, c, P);
        if (t0 + 32 < CHUNK) load_g16(g, t0 + 32, A);
        comp_sum16(B, c, P);
    }
    cLast[j * 8192 + bhd] = c;
    PLast[j * 8192 + bhd] = P;
}

__global__ __launch_bounds__(256) void scan_pass2(
    const __hip_bfloat16* __restrict__ gates,
    const float* __restrict__ cLast, const float* __restrict__ PLast,
    __hip_bfloat16* __restrict__ cbuf)
{
    int blk = blockIdx.x;              // 0..511
    int dh = blk & 1;
    int j  = (blk >> 1) & 15;
    int bh = blk >> 5;                 // 0..15
    int b = bh >> 2, h = bh & 3;
    int d = dh * 256 + threadIdx.x;    // 0..511
    int bhd = bh * 512 + d;

    // compose c_init for chunk j from preceding chunk summaries (exact f32)
    float c = 0.0f;
    for (int k = 0; k < j; ++k)
        c = fmaf(PLast[k * 8192 + bhd], c, cLast[k * 8192 + bhd]);

    const unsigned short* g = (const unsigned short*)gates
        + (size_t)(b * SEQ + j * CHUNK) * G4 + h * 2048 + d;
    __hip_bfloat16* cb = cbuf
        + (size_t)(b * SEQ + j * CHUNK) * HIDDEN + h * 512 + d;

    G16 A, B;
    load_g16(g, 0, A);
    for (int t0 = 0; t0 < CHUNK; t0 += 32) {
        load_g16(g, t0 + 16, B);
        c = comp_store16(A, c, cb, t0);
        if (t0 + 32 < CHUNK) load_g16(g, t0 + 32, A);
        c = comp_store16(B, c, cb, t0 + 16);
    }
}

// ---------------------------------------------------------------------------
// RMS-norm over HD=512 per (b,t,h), then h = o * tanh(c_norm). One wave per
// (b,t,h), 8 dims/lane, shuffle reduction. Writes h (bf16) IN-PLACE into the
// i-gate slot of gates (col h*2048 + d) for GEMM3's head-gather A staging.
// ---------------------------------------------------------------------------
__global__ __launch_bounds__(64) void norm_kernel(
    const __hip_bfloat16* __restrict__ cbuf, __hip_bfloat16* __restrict__ gates,
    const float* __restrict__ rms_w)
{
    int blk = blockIdx.x;                 // B*SEQ*H = 32768
    int h = blk & 3;
    int t = (blk >> 2) & (SEQ - 1);
    int b = blk >> 13;
    int lane = threadIdx.x;
    size_t tok = (size_t)(b * SEQ + t);

    BV8 cv; cv.u = *(const uint4*)(cbuf + tok * HIDDEN + h * 512 + lane * 8);
    float cf[8]; float s = 0.0f;
#pragma unroll
    for (int j = 0; j < 8; ++j) { cf[j] = b2f(cv.s[j]); s += cf[j] * cf[j]; }
#pragma unroll
    for (int off = 32; off > 0; off >>= 1) s += __shfl_xor(s, off, 64);
    float rs = rsqrtf(s * (1.0f / 512.0f) + EPSV);

    BV8 ov; ov.u = *(const uint4*)(gates + tok * G4 + h * 2048 + 1024 + lane * 8);
    float4 w0 = *(const float4*)&rms_w[lane * 8];
    float4 w1 = *(const float4*)&rms_w[lane * 8 + 4];
    float w[8] = { w0.x, w0.y, w0.z, w0.w, w1.x, w1.y, w1.z, w1.w };

    BV8 hv;
#pragma unroll
    for (int j = 0; j < 8; ++j) {
        float o = b2f(ov.s[j]);
        hv.h[j] = __float2bfloat16(o * fast_tanh(cf[j] * rs * w[j]));
    }
    *(uint4*)(gates + tok * G4 + h * 2048 + lane * 8) = hv.u;
}

// ---------------------------------------------------------------------------
// Workspace plan (192 MiB total, lifetime-aliased):
//  [0,  32MiB)  wgb (bf16 W_gate)   ... after GEMM2: [0,8M)=wob,
//                                       [8M,8.5M)=cLast, [8.5M,9M)=PLast
//  [32, 64MiB)  xpb (bf16 GEMM1 out)... after GEMM2: cbuf (bf16 c)
//  [64,192MiB)  gates (bf16)        ... before GEMM2: wib + xb
// ---------------------------------------------------------------------------
extern "C" void kernel_launch(void* const* d_in, const int* in_sizes, int n_in,
                              void* d_out, int out_size, void* d_ws, size_t ws_size,
                              hipStream_t stream)
{
    const float* x      = (const float*)d_in[0];   // (4,2048,2048)
    const float* W_in   = (const float*)d_in[1];   // (2048,2048)
    const float* W_gate = (const float*)d_in[2];   // (8192,2048)
    const float* b_gate = (const float*)d_in[3];   // (8192,)
    const float* rms_w  = (const float*)d_in[4];   // (512,)
    const float* W_out  = (const float*)d_in[5];   // (2048,2048)
    float* out = (float*)d_out;                    // (4,2048,2048)

    char* base = (char*)d_ws;
    __hip_bfloat16* wgb   = (__hip_bfloat16*)base;                             // 32 MiB
    __hip_bfloat16* xpb   = (__hip_bfloat16*)(base + (((size_t)32) << 20));    // 32 MiB
    __hip_bfloat16* gates = (__hip_bfloat16*)(base + (((size_t)64) << 20));    // 128 MiB
    // aliases (lifetime-disjoint, stream-ordered):
    __hip_bfloat16* wib  = gates;                                              // 8 MiB
    __hip_bfloat16* xb   = (__hip_bfloat16*)(base + (((size_t)72) << 20));     // 32 MiB
    __hip_bfloat16* wob  = wgb;                                                // 8 MiB
    float* cLast = (float*)(base + (((size_t)8) << 20));                       // 512 KiB
    float* PLast = (float*)(base + (((size_t)8) << 20) + (512 << 10));         // 512 KiB
    __hip_bfloat16* cbuf = xpb;                                                // 32 MiB

    // 1) casts to bf16 (wib/xb live in gates region; gates not written yet)
    cast_f32_bf16<<<(HIDDEN * DIMN) / 8 / 256, 256, 0, stream>>>(W_in, wib, (HIDDEN * DIMN) / 8);
    cast_f32_bf16<<<(NTOK * DIMN) / 8 / 256, 256, 0, stream>>>(x, xb, (NTOK * DIMN) / 8);
    cast_f32_bf16<<<(G4 * HIDDEN) / 8 / 256, 256, 0, stream>>>(W_gate, wgb, (G4 * HIDDEN) / 8);

    // 2) xp = x @ W_in^T  -> bf16
    {
        dim3 grid(HIDDEN / 128, NTOK / 128);
        gemm_bt<0, 0><<<grid, 256, 0, stream>>>(xb, wib, xpb, nullptr,
                                                NTOK, HIDDEN, DIMN, DIMN);
    }
    // 3) gates = act(xp @ W_gate^T + b) -> bf16 (overwrites wib/xb: dead now)
    {
        dim3 grid(G4 / 128, NTOK / 128);
        gemm_bt<1, 0><<<grid, 256, 0, stream>>>(xpb, wgb, gates, b_gate,
                                                NTOK, G4, HIDDEN, HIDDEN);
    }
    // 4) cast W_out -> wob (overwrites wgb: dead now)
    cast_f32_bf16<<<(DIMN * HIDDEN) / 8 / 256, 256, 0, stream>>>(W_out, wob, (DIMN * HIDDEN) / 8);

    // 5) chunk-decomposed scan -> cbuf (bf16; overwrites xpb: dead now)
    scan_pass1<<<BATCH * NHEADS * NCHUNK * 2, 256, 0, stream>>>(gates, cLast, PLast);
    scan_pass2<<<BATCH * NHEADS * NCHUNK * 2, 256, 0, stream>>>(gates, cLast, PLast, cbuf);

    // 6) RMS-norm + output gate; h written into gates i-slot
    norm_kernel<<<BATCH * SEQ * NHEADS, 64, 0, stream>>>(cbuf, gates, rms_w);

    // 7) out = h @ W_out^T -> f32 (A head-gathered from gates i-slot)
    {
        dim3 grid(DIMN / 128, NTOK / 128);
        gemm_bt<2, 1><<<grid, 256, 0, stream>>>(gates, wob, out, nullptr,
                                                NTOK, DIMN, HIDDEN, G4);
    }
}